// Round 6
// baseline (213.774 us; speedup 1.0000x reference)
//
#include <hip/hip_runtime.h>
#include <hip/hip_cooperative_groups.h>

namespace cg = cooperative_groups;

#define NF   16
#define C    8
#define NB   4
#define NPIX (512*512)

// One cooperative launch: 512 blocks (2/CU), 256 threads.
// Block g: batch b = g>>7, chunk blk = g&127 -> 2048 pixels.
#define NBLK    512
#define BPB     128                  // blocks per batch
#define SCHUNK  (NPIX / BPB)         // 2048 pixels per block
#define SITERS  (SCHUNK / (64 * 4))  // 8 load iterations per wave
#define DITERS  (SCHUNK / (256 * 4)) // 2 dist iterations per thread

// ws float layout (plain stores only; no atomics anywhere):
//   PSUM: [b][blk][128]  fc = f*8+c   NB*BPB*128 = 65536 floats
//   PCNT: [b][blk][8]                 NB*BPB*8   = 4096
//   POUT: [g]                         512
#define WS_PSUM 0
#define WS_PCNT (NB * BPB * 128)
#define WS_POUT (WS_PCNT + NB * BPB * 8)

__global__ __launch_bounds__(256) void fused_kernel(const float* __restrict__ pred,
                                                    const int* __restrict__ tgt,
                                                    float* __restrict__ ws,
                                                    float* __restrict__ out) {
    const int tid  = threadIdx.x;
    const int lane = tid & 63;
    const int wave = tid >> 6;          // 0..3
    const int g    = blockIdx.x;
    const int b    = g >> 7;
    const int blk  = g & (BPB - 1);
    const int f0   = wave * 4;          // this wave's features: f0..f0+3

    const float* predb = pred + (size_t)b * NF * NPIX;
    const int*   tgtb  = tgt  + (size_t)b * NPIX;
    const int start = blk * SCHUNK;

    __shared__ float smean_p[2][128];
    __shared__ float scnt_p[8][8];
    __shared__ float scnt[8];
    __shared__ float s_mean[128];
    __shared__ float s_invs;
    __shared__ float s_red[4];

    // ================= Phase 1: partial sums =================
    float acc[4][8];
#pragma unroll
    for (int i = 0; i < 4; ++i)
#pragma unroll
        for (int c = 0; c < 8; ++c) acc[i][c] = 0.0f;
    float cnt[8];
#pragma unroll
    for (int c = 0; c < 8; ++c) cnt[c] = 0.0f;

#pragma unroll 2
    for (int it = 0; it < SITERS; ++it) {
        const int base = start + it * 256 + lane * 4;
        int4 lab = *(const int4*)(tgtb + base);
        float4 p[4];
#pragma unroll
        for (int fi = 0; fi < 4; ++fi)
            p[fi] = *(const float4*)(predb + (f0 + fi) * NPIX + base);

        const int labs[4] = { lab.x, lab.y, lab.z, lab.w };
#pragma unroll
        for (int px = 0; px < 4; ++px) {
            const int lv = labs[px];
            float m[8];
#pragma unroll
            for (int c = 0; c < 8; ++c) m[c] = (lv == c) ? 1.0f : 0.0f;
            if (wave == 0) {
#pragma unroll
                for (int c = 0; c < 8; ++c) cnt[c] += m[c];
            }
#pragma unroll
            for (int fi = 0; fi < 4; ++fi) {
                const float pv = (px == 0) ? p[fi].x :
                                 (px == 1) ? p[fi].y :
                                 (px == 2) ? p[fi].z : p[fi].w;
#pragma unroll
                for (int c = 0; c < 8; ++c) acc[fi][c] += m[c] * pv;
            }
        }
    }

    // xor-butterfly: every lane ends with the full 64-lane total
#pragma unroll
    for (int off = 32; off > 0; off >>= 1) {
#pragma unroll
        for (int fi = 0; fi < 4; ++fi)
#pragma unroll
            for (int c = 0; c < 8; ++c)
                acc[fi][c] += __shfl_xor(acc[fi][c], off);
    }
    if (wave == 0) {
#pragma unroll
        for (int off = 32; off > 0; off >>= 1)
#pragma unroll
            for (int c = 0; c < 8; ++c)
                cnt[c] += __shfl_xor(cnt[c], off);
    }

    // commit: lane l<32 owns fc = f0*8+l -> one coalesced 128B store per wave
    {
        float v = 0.0f;
#pragma unroll
        for (int fj = 0; fj < 4; ++fj)
#pragma unroll
            for (int cj = 0; cj < 8; ++cj)
                v = (lane == fj * 8 + cj) ? acc[fj][cj] : v;
        if (lane < 32)
            ws[WS_PSUM + ((size_t)(b * BPB + blk)) * 128 + f0 * 8 + lane] = v;
        if (wave == 0) {
            float cv = 0.0f;
#pragma unroll
            for (int cj = 0; cj < 8; ++cj)
                cv = (lane == 32 + cj) ? cnt[cj] : cv;
            if (lane >= 32 && lane < 40)
                ws[WS_PCNT + (b * BPB + blk) * 8 + (lane - 32)] = cv;
        }
    }

    cg::this_grid().sync();

    // ======= Phase 2: per-block means for batch b (LDS only) =======
    // counts: t<64 -> c = t&7, grp = t>>3 sums 16 parts
    if (tid < 64) {
        const int c = tid & 7, grp = tid >> 3;
        float s = 0.0f;
#pragma unroll
        for (int i = 0; i < 16; ++i)
            s += ws[WS_PCNT + (b * BPB + grp * 16 + i) * 8 + c];
        scnt_p[grp][c] = s;
    }
    // means: fc = t&127, half = t>>7 sums 64 parts (coalesced over t)
    {
        const int fc = tid & 127, half = tid >> 7;
        float s = 0.0f;
        for (int i = 0; i < 64; ++i)
            s += ws[WS_PSUM + ((size_t)(b * BPB + half * 64 + i)) * 128 + fc];
        smean_p[half][fc] = s;
    }
    __syncthreads();
    if (tid < 8) {
        float s = 0.0f;
#pragma unroll
        for (int grp = 0; grp < 8; ++grp) s += scnt_p[grp][tid];
        scnt[tid] = s;
    }
    __syncthreads();
    if (tid < 128)
        s_mean[tid] = (smean_p[0][tid] + smean_p[1][tid]) / scnt[tid & 7];
    if (tid == 0) {
        float iv = 0.0f;
#pragma unroll
        for (int c = 0; c < 8; ++c) iv += 1.0f / scnt[c];
        s_invs = iv;
    }
    __syncthreads();

    // ================= Phase 3: distance partial =================
    float dacc = 0.0f;
#pragma unroll
    for (int it = 0; it < DITERS; ++it) {
        const int base = start + it * 1024 + tid * 4;
        int4 lab = *(const int4*)(tgtb + base);
        float s0 = 0.f, s1 = 0.f, s2 = 0.f, s3 = 0.f;
#pragma unroll
        for (int f = 0; f < NF; ++f) {
            float4 p = *(const float4*)(predb + f * NPIX + base);
            float d0 = s_mean[f * C + lab.x] - p.x;
            float d1 = s_mean[f * C + lab.y] - p.y;
            float d2 = s_mean[f * C + lab.z] - p.z;
            float d3 = s_mean[f * C + lab.w] - p.w;
            s0 += d0 * d0; s1 += d1 * d1; s2 += d2 * d2; s3 += d3 * d3;
        }
        float t0 = fminf(fmaxf(sqrtf(s0) - 0.5f, 0.0f), 100000.0f);
        float t1 = fminf(fmaxf(sqrtf(s1) - 0.5f, 0.0f), 100000.0f);
        float t2 = fminf(fmaxf(sqrtf(s2) - 0.5f, 0.0f), 100000.0f);
        float t3 = fminf(fmaxf(sqrtf(s3) - 0.5f, 0.0f), 100000.0f);
        dacc += t0 * t0 + t1 * t1 + t2 * t2 + t3 * t3;
    }
#pragma unroll
    for (int off = 32; off > 0; off >>= 1) dacc += __shfl_down(dacc, off);
    if (lane == 0) s_red[wave] = dacc;
    __syncthreads();
    if (tid == 0) {
        float tot = s_red[0] + s_red[1] + s_red[2] + s_red[3];
        ws[WS_POUT + g] = tot * s_invs * 0.125f;
    }

    cg::this_grid().sync();

    // ================= Phase 4: final reduce (block 0) =================
    if (g == 0) {
        float v = ws[WS_POUT + tid] + ws[WS_POUT + tid + 256];
#pragma unroll
        for (int off = 32; off > 0; off >>= 1) v += __shfl_xor(v, off);
        if (lane == 0) s_red[wave] = v;
        __syncthreads();
        if (tid == 0)
            out[0] = s_red[0] + s_red[1] + s_red[2] + s_red[3];
    }
}

extern "C" void kernel_launch(void* const* d_in, const int* in_sizes, int n_in,
                              void* d_out, int out_size, void* d_ws, size_t ws_size,
                              hipStream_t stream) {
    const float* pred = (const float*)d_in[0];
    const int*   tgt  = (const int*)d_in[1];
    float* out = (float*)d_out;
    float* ws  = (float*)d_ws;

    void* args[] = { (void*)&pred, (void*)&tgt, (void*)&ws, (void*)&out };
    hipLaunchCooperativeKernel((const void*)fused_kernel, dim3(NBLK), dim3(256),
                               args, 0, stream);
}

// Round 7
// 121.723 us; speedup vs baseline: 1.7562x; 1.7562x over previous
//
#include <hip/hip_runtime.h>

#define NF   16
#define C    8
#define NB   4
#define NPIX (512*512)

// sums: 512-px LDS-staged tiles; 512 blocks per batch, 4 blocks/CU (34 KB LDS)
#define SBPB   512
#define SPX    512
// dist: 1024-px LDS-staged tiles; 256 blocks per batch, 2 blocks/CU (68.6 KB LDS)
#define DBPB   256
#define DPX    1024

// ws float layout (plain stores only; no atomics anywhere):
//   PSUM: [b][blk][128]  fc = f*8+c   NB*SBPB*128 = 262144 floats
//   PCNT: [b][blk][8]                 NB*SBPB*8   = 16384
//   MEAN: [b][128]       fc = f*8+c   512
//   INV:  [b]                         4
//   POUT: [b][DBPB]                   1024
#define WS_PSUM 0
#define WS_PCNT (NB * SBPB * 128)
#define WS_MEAN (WS_PCNT + NB * SBPB * 8)
#define WS_INV  (WS_MEAN + NB * 128)
#define WS_POUT (WS_INV + NB)

// Async global->LDS, 16B per lane, no VGPR destination: the compiler cannot
// re-serialize these into load-use pairs (rounds 2/6 showed reg-staged loads
// collapse to ~1-2 in flight at VGPR_Count=52). LDS dest = uniform base +
// lane*16, so the destination must be linear/contiguous per wave.
__device__ __forceinline__ void gload_lds16(const void* g, void* l) {
    __builtin_amdgcn_global_load_lds((const __attribute__((address_space(1))) void*)g,
                                     (__attribute__((address_space(3))) void*)l,
                                     16, 0, 0);
}

__global__ __launch_bounds__(256) void sums_kernel(const float* __restrict__ pred,
                                                   const int* __restrict__ tgt,
                                                   float* __restrict__ ws) {
    __shared__ float pred_s[NF * SPX];   // 32 KB
    __shared__ int   tgt_s[SPX];         // 2 KB
    const int tid  = threadIdx.x;
    const int lane = tid & 63;
    const int wave = tid >> 6;          // 0..3
    const int b    = blockIdx.y;
    const int blk  = blockIdx.x;
    const int f0   = wave * 4;          // this wave's features

    const float* predb = pred + (size_t)b * NF * NPIX;
    const int*   tgtb  = tgt  + (size_t)b * NPIX;
    const int S = blk * SPX;

    // ---- stage: wave w fires 8x 1KB async loads for its 4 feature rows;
    //      wave 0 also stages the 512 labels (2x 1KB). Fire-and-forget. ----
#pragma unroll
    for (int fi = 0; fi < 4; ++fi)
#pragma unroll
        for (int half = 0; half < 2; ++half)
            gload_lds16(predb + (f0 + fi) * NPIX + S + half * 256 + lane * 4,
                        &pred_s[(f0 + fi) * SPX + half * 256]);
    if (wave == 0) {
#pragma unroll
        for (int half = 0; half < 2; ++half)
            gload_lds16(tgtb + S + half * 256 + lane * 4, &tgt_s[half * 256]);
    }
    __syncthreads();   // single vmcnt(0) drain; inter-block overlap hides it

    // ---- compute from LDS: 2 iterations of the 4-px masked-FMA body ----
    float acc[4][8];
#pragma unroll
    for (int i = 0; i < 4; ++i)
#pragma unroll
        for (int c = 0; c < 8; ++c) acc[i][c] = 0.0f;
    float cnt[8];
#pragma unroll
    for (int c = 0; c < 8; ++c) cnt[c] = 0.0f;

#pragma unroll
    for (int it = 0; it < SPX / 256; ++it) {
        const int pxb = it * 256 + lane * 4;
        int4 lab = *(const int4*)&tgt_s[pxb];
        float4 p[4];
#pragma unroll
        for (int fi = 0; fi < 4; ++fi)
            p[fi] = *(const float4*)&pred_s[(f0 + fi) * SPX + pxb];

        const int labs[4] = { lab.x, lab.y, lab.z, lab.w };
#pragma unroll
        for (int px = 0; px < 4; ++px) {
            const int lv = labs[px];
            float m[8];
#pragma unroll
            for (int c = 0; c < 8; ++c) m[c] = (lv == c) ? 1.0f : 0.0f;
            if (wave == 0) {
#pragma unroll
                for (int c = 0; c < 8; ++c) cnt[c] += m[c];
            }
#pragma unroll
            for (int fi = 0; fi < 4; ++fi) {
                const float pv = (px == 0) ? p[fi].x :
                                 (px == 1) ? p[fi].y :
                                 (px == 2) ? p[fi].z : p[fi].w;
#pragma unroll
                for (int c = 0; c < 8; ++c) acc[fi][c] += m[c] * pv;
            }
        }
    }

    // xor-butterfly: every lane ends with the full 64-lane total
#pragma unroll
    for (int off = 32; off > 0; off >>= 1) {
#pragma unroll
        for (int fi = 0; fi < 4; ++fi)
#pragma unroll
            for (int c = 0; c < 8; ++c)
                acc[fi][c] += __shfl_xor(acc[fi][c], off);
    }
    if (wave == 0) {
#pragma unroll
        for (int off = 32; off > 0; off >>= 1)
#pragma unroll
            for (int c = 0; c < 8; ++c)
                cnt[c] += __shfl_xor(cnt[c], off);
    }

    // commit: lane l<32 owns fc = f0*8+l -> one coalesced 128B store per wave
    {
        float v = 0.0f;
#pragma unroll
        for (int fj = 0; fj < 4; ++fj)
#pragma unroll
            for (int cj = 0; cj < 8; ++cj)
                v = (lane == fj * 8 + cj) ? acc[fj][cj] : v;
        if (lane < 32)
            ws[WS_PSUM + ((size_t)(b * SBPB + blk)) * 128 + f0 * 8 + lane] = v;
        if (wave == 0) {
            float cv = 0.0f;
#pragma unroll
            for (int cj = 0; cj < 8; ++cj)
                cv = (lane == 32 + cj) ? cnt[cj] : cv;
            if (lane >= 32 && lane < 40)
                ws[WS_PCNT + (b * SBPB + blk) * 8 + (lane - 32)] = cv;
        }
    }
}

// 32 blocks (8 fc-groups x 4 batches), 256 threads; SBPB=512 partials each.
__global__ void means_kernel(float* __restrict__ ws) {
    __shared__ float scnt_p[32 * 8];
    __shared__ float scnt[8];
    __shared__ float smean[16 * 16];
    const int t = threadIdx.x, g = blockIdx.x, b = blockIdx.y;

    // counts: c = t&7, part = t>>3 -> 32 parts x 16 blks = 512
    {
        const int c = t & 7, part = t >> 3;
        float s = 0.0f;
#pragma unroll
        for (int i = 0; i < 16; ++i)
            s += ws[WS_PCNT + (b * SBPB + part * 16 + i) * 8 + c];
        scnt_p[part * 8 + c] = s;
    }
    __syncthreads();
    if (t < 8) {
        float s = 0.0f;
        for (int p = 0; p < 32; ++p) s += scnt_p[p * 8 + t];
        scnt[t] = s;
    }
    __syncthreads();

    // means for fc in [g*16, g*16+16): fcl = t&15, part = t>>4 -> 16 x 32 blks
    {
        const int fcl = t & 15, part = t >> 4;
        const int fc = g * 16 + fcl;
        float s = 0.0f;
#pragma unroll
        for (int i = 0; i < 32; ++i)
            s += ws[WS_PSUM + (size_t)(b * SBPB + part * 32 + i) * 128 + fc];
        smean[part * 16 + fcl] = s;
    }
    __syncthreads();
    if (t < 16) {
        float s = 0.0f;
        for (int p = 0; p < 16; ++p) s += smean[p * 16 + t];
        const int fc = g * 16 + t;
        ws[WS_MEAN + b * 128 + fc] = s / scnt[fc & 7];
    }
    if (g == 0 && t == 0) {
        float iv = 0.0f;
#pragma unroll
        for (int c = 0; c < 8; ++c) iv += 1.0f / scnt[c];
        ws[WS_INV + b] = iv;
    }
}

__global__ __launch_bounds__(256) void dist_kernel(const float* __restrict__ pred,
                                                   const int* __restrict__ tgt,
                                                   const float* __restrict__ ws,
                                                   float* __restrict__ pout) {
    __shared__ float pred_s[NF * DPX];   // 64 KB
    __shared__ int   tgt_s[DPX];         // 4 KB
    __shared__ float s_mean[128];
    __shared__ float s_red[4];
    const int tid  = threadIdx.x;
    const int lane = tid & 63;
    const int wave = tid >> 6;
    const int b    = blockIdx.y;
    const int blk  = blockIdx.x;
    const int f0   = wave * 4;

    const float* predb = pred + (size_t)b * NF * NPIX;
    const int*   tgtb  = tgt  + (size_t)b * NPIX;
    const int S = blk * DPX;

    // stage: wave w fires 16x 1KB loads for its 4 feature rows; wave 0 labels.
#pragma unroll
    for (int fi = 0; fi < 4; ++fi)
#pragma unroll
        for (int q = 0; q < 4; ++q)
            gload_lds16(predb + (f0 + fi) * NPIX + S + q * 256 + lane * 4,
                        &pred_s[(f0 + fi) * DPX + q * 256]);
    if (wave == 0) {
#pragma unroll
        for (int q = 0; q < 4; ++q)
            gload_lds16(tgtb + S + q * 256 + lane * 4, &tgt_s[q * 256]);
    }
    if (tid < 128) s_mean[tid] = ws[WS_MEAN + b * 128 + tid];
    const float invs = ws[WS_INV + b];
    __syncthreads();

    // compute: thread owns 4 px at tid*4, all from LDS
    const int pxb = tid * 4;
    int4 lab = *(const int4*)&tgt_s[pxb];
    float s0 = 0.f, s1 = 0.f, s2 = 0.f, s3 = 0.f;
#pragma unroll
    for (int f = 0; f < NF; ++f) {
        float4 p = *(const float4*)&pred_s[f * DPX + pxb];
        float d0 = s_mean[f * C + lab.x] - p.x;
        float d1 = s_mean[f * C + lab.y] - p.y;
        float d2 = s_mean[f * C + lab.z] - p.z;
        float d3 = s_mean[f * C + lab.w] - p.w;
        s0 += d0 * d0; s1 += d1 * d1; s2 += d2 * d2; s3 += d3 * d3;
    }
    float t0 = fminf(fmaxf(sqrtf(s0) - 0.5f, 0.0f), 100000.0f);
    float t1 = fminf(fmaxf(sqrtf(s1) - 0.5f, 0.0f), 100000.0f);
    float t2 = fminf(fmaxf(sqrtf(s2) - 0.5f, 0.0f), 100000.0f);
    float t3 = fminf(fmaxf(sqrtf(s3) - 0.5f, 0.0f), 100000.0f);
    float acc = t0 * t0 + t1 * t1 + t2 * t2 + t3 * t3;

#pragma unroll
    for (int off = 32; off > 0; off >>= 1) acc += __shfl_down(acc, off);
    if (lane == 0) s_red[wave] = acc;
    __syncthreads();
    if (tid == 0) {
        float tot = s_red[0] + s_red[1] + s_red[2] + s_red[3];
        pout[b * DBPB + blk] = tot * invs * 0.125f;
    }
}

// One block, 512 threads: sum the 1024 dist partials, plain store to out.
__global__ void final_kernel(const float* __restrict__ pout, float* __restrict__ out) {
    __shared__ float sr[8];
    const int t = threadIdx.x;
    float v = pout[t] + pout[t + 512];
#pragma unroll
    for (int off = 32; off > 0; off >>= 1) v += __shfl_xor(v, off);
    if ((t & 63) == 0) sr[t >> 6] = v;
    __syncthreads();
    if (t == 0) {
        float s = 0.0f;
#pragma unroll
        for (int i = 0; i < 8; ++i) s += sr[i];
        out[0] = s;
    }
}

extern "C" void kernel_launch(void* const* d_in, const int* in_sizes, int n_in,
                              void* d_out, int out_size, void* d_ws, size_t ws_size,
                              hipStream_t stream) {
    const float* pred = (const float*)d_in[0];
    const int*   tgt  = (const int*)d_in[1];
    float* out = (float*)d_out;
    float* ws  = (float*)d_ws;

    sums_kernel<<<dim3(SBPB, NB), dim3(256), 0, stream>>>(pred, tgt, ws);
    means_kernel<<<dim3(8, NB), dim3(256), 0, stream>>>(ws);
    dist_kernel<<<dim3(DBPB, NB), dim3(256), 0, stream>>>(pred, tgt, ws, ws + WS_POUT);
    final_kernel<<<dim3(1), dim3(512), 0, stream>>>(ws + WS_POUT, out);
}

// Round 8
// 119.008 us; speedup vs baseline: 1.7963x; 1.0228x over previous
//
#include <hip/hip_runtime.h>

#define NF   16
#define C    8
#define NB   4
#define NPIX (512*512)

// plane-major sums: grid (CH, NF, NB) = 1024 blocks. Each block streams one
// CONTIGUOUS 64KB span of ONE feature plane + the matching 64KB label span.
// 2 linear streams per block instead of 5 interleaved 1MB-spaced streams.
#define CH      16
#define CPX     (NPIX / CH)          // 16384 px per chunk
#define SITERS  (CPX / (256 * 4))    // 16 iterations, 4 px per thread each

// dist: DG blocks per batch, 256 threads, 4 px per thread (R5 structure)
#define DG      256
#define DCHUNK  (NPIX / DG)          // 1024 px per block

// ws float layout (plain stores only; no atomics anywhere):
//   PSUM: [b][f][ch][8]   4*16*16*8 = 8192 floats
//   PCNT: [b][ch][8]      4*16*8    = 512
//   MEAN: [b][128]  fc = f*8+c      512
//   INV:  [b]                       4
//   POUT: [b][DG]                   1024
#define WS_PSUM 0
#define WS_PCNT (NB * NF * CH * 8)
#define WS_MEAN (WS_PCNT + NB * CH * 8)
#define WS_INV  (WS_MEAN + NB * 128)
#define WS_POUT (WS_INV + NB)

__global__ __launch_bounds__(256) void sums_kernel(const float* __restrict__ pred,
                                                   const int* __restrict__ tgt,
                                                   float* __restrict__ ws) {
    const int t    = threadIdx.x;
    const int lane = t & 63;
    const int wave = t >> 6;            // 0..3
    const int ch   = blockIdx.x;
    const int f    = blockIdx.y;
    const int b    = blockIdx.z;

    const float* pf = pred + ((size_t)b * NF + f) * NPIX + ch * CPX;
    const int*   tg = tgt  + (size_t)b * NPIX + ch * CPX;

    float acc[8];
#pragma unroll
    for (int c = 0; c < 8; ++c) acc[c] = 0.0f;
    float cnt[8];
#pragma unroll
    for (int c = 0; c < 8; ++c) cnt[c] = 0.0f;

    for (int it = 0; it < SITERS; ++it) {
        const int px = it * 1024 + t * 4;
        int4   lab = *(const int4*)(tg + px);
        float4 p   = *(const float4*)(pf + px);
        float m0[8], m1[8], m2[8], m3[8];
#pragma unroll
        for (int c = 0; c < 8; ++c) {
            m0[c] = (lab.x == c) ? 1.0f : 0.0f;
            m1[c] = (lab.y == c) ? 1.0f : 0.0f;
            m2[c] = (lab.z == c) ? 1.0f : 0.0f;
            m3[c] = (lab.w == c) ? 1.0f : 0.0f;
        }
#pragma unroll
        for (int c = 0; c < 8; ++c)
            acc[c] += m0[c] * p.x + m1[c] * p.y + m2[c] * p.z + m3[c] * p.w;
        if (f == 0) {
#pragma unroll
            for (int c = 0; c < 8; ++c)
                cnt[c] += m0[c] + m1[c] + m2[c] + m3[c];
        }
    }

    // wave butterfly, then cross-wave via LDS
#pragma unroll
    for (int off = 32; off > 0; off >>= 1)
#pragma unroll
        for (int c = 0; c < 8; ++c)
            acc[c] += __shfl_xor(acc[c], off);
    if (f == 0) {
#pragma unroll
        for (int off = 32; off > 0; off >>= 1)
#pragma unroll
            for (int c = 0; c < 8; ++c)
                cnt[c] += __shfl_xor(cnt[c], off);
    }

    __shared__ float sred[4][8];
    __shared__ float scred[4][8];
    if (lane == 0) {
#pragma unroll
        for (int c = 0; c < 8; ++c) sred[wave][c] = acc[c];
        if (f == 0)
#pragma unroll
            for (int c = 0; c < 8; ++c) scred[wave][c] = cnt[c];
    }
    __syncthreads();
    if (t < 8)
        ws[WS_PSUM + (((size_t)b * NF + f) * CH + ch) * 8 + t] =
            sred[0][t] + sred[1][t] + sred[2][t] + sred[3][t];
    if (f == 0 && t >= 8 && t < 16) {
        const int c = t - 8;
        ws[WS_PCNT + (b * CH + ch) * 8 + c] =
            scred[0][c] + scred[1][c] + scred[2][c] + scred[3][c];
    }
}

// One block, 512 threads: reduce 16 chunk-partials per (b,fc), means + invsum.
__global__ void means_kernel(float* __restrict__ ws) {
    __shared__ float scnt[32];
    const int t = threadIdx.x;
    if (t < 32) {
        const int b = t >> 3, c = t & 7;
        float s = 0.0f;
#pragma unroll
        for (int ch = 0; ch < CH; ++ch)
            s += ws[WS_PCNT + (b * CH + ch) * 8 + c];
        scnt[t] = s;
    }
    __syncthreads();
    const int b = t >> 7, fc = t & 127, f = fc >> 3, c = fc & 7;
    float s = 0.0f;
#pragma unroll
    for (int ch = 0; ch < CH; ++ch)
        s += ws[WS_PSUM + (((size_t)b * NF + f) * CH + ch) * 8 + c];
    ws[WS_MEAN + b * 128 + fc] = s / scnt[b * 8 + c];
    if (fc == 0) {
        float iv = 0.0f;
#pragma unroll
        for (int c8 = 0; c8 < 8; ++c8) iv += 1.0f / scnt[b * 8 + c8];
        ws[WS_INV + b] = iv;
    }
}

// R5 dist: per-block partial, straight-line single iteration, plain store.
__global__ __launch_bounds__(256) void dist_kernel(const float* __restrict__ pred,
                                                   const int* __restrict__ tgt,
                                                   const float* __restrict__ ws,
                                                   float* __restrict__ pout) {
    __shared__ float s_means[C * NF];
    __shared__ float s_red[4];
    const int tid = threadIdx.x;
    const int b   = blockIdx.y;
    if (tid < C * NF) s_means[tid] = ws[WS_MEAN + b * 128 + tid];
    const float invs = ws[WS_INV + b];
    __syncthreads();

    const float* predb = pred + (size_t)b * NF * NPIX;
    const int*   tgtb  = tgt  + (size_t)b * NPIX;

    const int base = blockIdx.x * DCHUNK + tid * 4;
    int4 lab = *(const int4*)(tgtb + base);
    float s0 = 0.f, s1 = 0.f, s2 = 0.f, s3 = 0.f;
#pragma unroll
    for (int f = 0; f < NF; ++f) {
        float4 p = *(const float4*)(predb + f * NPIX + base);
        float d0 = s_means[f * C + lab.x] - p.x;
        float d1 = s_means[f * C + lab.y] - p.y;
        float d2 = s_means[f * C + lab.z] - p.z;
        float d3 = s_means[f * C + lab.w] - p.w;
        s0 += d0 * d0; s1 += d1 * d1; s2 += d2 * d2; s3 += d3 * d3;
    }
    float t0 = fminf(fmaxf(sqrtf(s0) - 0.5f, 0.0f), 100000.0f);
    float t1 = fminf(fmaxf(sqrtf(s1) - 0.5f, 0.0f), 100000.0f);
    float t2 = fminf(fmaxf(sqrtf(s2) - 0.5f, 0.0f), 100000.0f);
    float t3 = fminf(fmaxf(sqrtf(s3) - 0.5f, 0.0f), 100000.0f);
    float acc = t0 * t0 + t1 * t1 + t2 * t2 + t3 * t3;

#pragma unroll
    for (int off = 32; off > 0; off >>= 1) acc += __shfl_down(acc, off);
    const int lane = tid & 63, wave = tid >> 6;
    if (lane == 0) s_red[wave] = acc;
    __syncthreads();
    if (tid == 0) {
        float tot = s_red[0] + s_red[1] + s_red[2] + s_red[3];
        pout[b * DG + blockIdx.x] = tot * invs * 0.125f;
    }
}

// One block, 512 threads: sum the 1024 dist partials, plain store to out.
__global__ void final_kernel(const float* __restrict__ pout, float* __restrict__ out) {
    __shared__ float sr[8];
    const int t = threadIdx.x;
    float v = pout[t] + pout[t + 512];
#pragma unroll
    for (int off = 32; off > 0; off >>= 1) v += __shfl_xor(v, off);
    if ((t & 63) == 0) sr[t >> 6] = v;
    __syncthreads();
    if (t == 0) {
        float s = 0.0f;
#pragma unroll
        for (int i = 0; i < 8; ++i) s += sr[i];
        out[0] = s;
    }
}

extern "C" void kernel_launch(void* const* d_in, const int* in_sizes, int n_in,
                              void* d_out, int out_size, void* d_ws, size_t ws_size,
                              hipStream_t stream) {
    const float* pred = (const float*)d_in[0];
    const int*   tgt  = (const int*)d_in[1];
    float* out = (float*)d_out;
    float* ws  = (float*)d_ws;

    sums_kernel<<<dim3(CH, NF, NB), dim3(256), 0, stream>>>(pred, tgt, ws);
    means_kernel<<<dim3(1), dim3(512), 0, stream>>>(ws);
    dist_kernel<<<dim3(DG, NB), dim3(256), 0, stream>>>(pred, tgt, ws, ws + WS_POUT);
    final_kernel<<<dim3(1), dim3(512), 0, stream>>>(ws + WS_POUT, out);
}

// Round 9
// 118.667 us; speedup vs baseline: 1.8015x; 1.0029x over previous
//
#include <hip/hip_runtime.h>

#define NF   16
#define C    8
#define NB   4
#define NPIX (512*512)

// plane-major sums: grid (CH, NF, NB) = 4096 blocks -> 8+ blocks/CU (occupancy
// lever: every prior variant ran <=4 blocks/CU at 22-30% occupancy).
// Each block streams one contiguous 16KB span of ONE feature plane + the
// matching 16KB label span. Default round-robin puts the 16 f-blocks of a
// chunk on the same XCD (id%8 == ch%8) -> label re-reads are L2 hits.
#define CH      64
#define CPX     (NPIX / CH)          // 4096 px per chunk
#define SITERS  (CPX / (256 * 4))    // 4 iterations, 4 px per thread each

// dist: DG blocks per batch; each block redundantly reduces means from the
// tiny PSUM (32KB/batch, L2-fast) -> no separate means kernel, one less gap.
#define DG      256
#define DCHUNK  (NPIX / DG)          // 1024 px per block

// ws float layout (plain stores only; no atomics anywhere):
//   PSUM: [b][f][ch][8]   4*16*64*8 = 32768 floats
//   PCNT: [b][ch][8]      4*64*8    = 2048
//   POUT: [b][DG]                     1024
#define WS_PSUM 0
#define WS_PCNT (NB * NF * CH * 8)
#define WS_POUT (WS_PCNT + NB * CH * 8)

__global__ __launch_bounds__(256) void sums_kernel(const float* __restrict__ pred,
                                                   const int* __restrict__ tgt,
                                                   float* __restrict__ ws) {
    const int t    = threadIdx.x;
    const int lane = t & 63;
    const int wave = t >> 6;            // 0..3
    const int ch   = blockIdx.x;
    const int f    = blockIdx.y;
    const int b    = blockIdx.z;

    const float* pf = pred + ((size_t)b * NF + f) * NPIX + ch * CPX;
    const int*   tg = tgt  + (size_t)b * NPIX + ch * CPX;

    float acc[8];
#pragma unroll
    for (int c = 0; c < 8; ++c) acc[c] = 0.0f;
    float cnt[8];
#pragma unroll
    for (int c = 0; c < 8; ++c) cnt[c] = 0.0f;

#pragma unroll
    for (int it = 0; it < SITERS; ++it) {
        const int px = it * 1024 + t * 4;
        int4   lab = *(const int4*)(tg + px);
        float4 p   = *(const float4*)(pf + px);
        float m0[8], m1[8], m2[8], m3[8];
#pragma unroll
        for (int c = 0; c < 8; ++c) {
            m0[c] = (lab.x == c) ? 1.0f : 0.0f;
            m1[c] = (lab.y == c) ? 1.0f : 0.0f;
            m2[c] = (lab.z == c) ? 1.0f : 0.0f;
            m3[c] = (lab.w == c) ? 1.0f : 0.0f;
        }
#pragma unroll
        for (int c = 0; c < 8; ++c)
            acc[c] += m0[c] * p.x + m1[c] * p.y + m2[c] * p.z + m3[c] * p.w;
        if (f == 0) {
#pragma unroll
            for (int c = 0; c < 8; ++c)
                cnt[c] += m0[c] + m1[c] + m2[c] + m3[c];
        }
    }

    // wave butterfly, then cross-wave via LDS
#pragma unroll
    for (int off = 32; off > 0; off >>= 1)
#pragma unroll
        for (int c = 0; c < 8; ++c)
            acc[c] += __shfl_xor(acc[c], off);
    if (f == 0) {
#pragma unroll
        for (int off = 32; off > 0; off >>= 1)
#pragma unroll
            for (int c = 0; c < 8; ++c)
                cnt[c] += __shfl_xor(cnt[c], off);
    }

    __shared__ float sred[4][8];
    __shared__ float scred[4][8];
    if (lane == 0) {
#pragma unroll
        for (int c = 0; c < 8; ++c) sred[wave][c] = acc[c];
        if (f == 0)
#pragma unroll
            for (int c = 0; c < 8; ++c) scred[wave][c] = cnt[c];
    }
    __syncthreads();
    if (t < 8)
        ws[WS_PSUM + (((size_t)b * NF + f) * CH + ch) * 8 + t] =
            sred[0][t] + sred[1][t] + sred[2][t] + sred[3][t];
    if (f == 0 && t >= 8 && t < 16) {
        const int c = t - 8;
        ws[WS_PCNT + (b * CH + ch) * 8 + c] =
            scred[0][c] + scred[1][c] + scred[2][c] + scred[3][c];
    }
}

// dist with in-block means reduction (redundant per block; PSUM+PCNT are
// ~34KB/batch and L2/L3-resident after sums).
__global__ __launch_bounds__(256) void dist_kernel(const float* __restrict__ pred,
                                                   const int* __restrict__ tgt,
                                                   const float* __restrict__ ws,
                                                   float* __restrict__ pout) {
    __shared__ float sm_p[2][128];
    __shared__ float scnt_p[8][8];
    __shared__ float scnt[8];
    __shared__ float s_means[128];
    __shared__ float s_invs;
    __shared__ float s_red[4];
    const int tid = threadIdx.x;
    const int b   = blockIdx.y;

    // counts: t<64 -> c=t&7, grp=t>>3 sums 8 chunks
    if (tid < 64) {
        const int c = tid & 7, grp = tid >> 3;
        float s = 0.0f;
#pragma unroll
        for (int i = 0; i < 8; ++i)
            s += ws[WS_PCNT + (b * CH + grp * 8 + i) * 8 + c];
        scnt_p[grp][c] = s;
    }
    // sums: fc = t&127, half = t>>7 sums 32 chunks each
    {
        const int fc = tid & 127, half = tid >> 7;
        const int f = fc >> 3, c = fc & 7;
        float s = 0.0f;
#pragma unroll
        for (int i = 0; i < 32; ++i)
            s += ws[WS_PSUM + (((size_t)b * NF + f) * CH + half * 32 + i) * 8 + c];
        sm_p[half][fc] = s;
    }
    __syncthreads();
    if (tid < 8) {
        float s = 0.0f;
#pragma unroll
        for (int grp = 0; grp < 8; ++grp) s += scnt_p[grp][tid];
        scnt[tid] = s;
    }
    __syncthreads();
    if (tid < 128)
        s_means[tid] = (sm_p[0][tid] + sm_p[1][tid]) / scnt[tid & 7];
    if (tid == 0) {
        float iv = 0.0f;
#pragma unroll
        for (int c = 0; c < 8; ++c) iv += 1.0f / scnt[c];
        s_invs = iv;
    }
    __syncthreads();

    const float* predb = pred + (size_t)b * NF * NPIX;
    const int*   tgtb  = tgt  + (size_t)b * NPIX;

    const int base = blockIdx.x * DCHUNK + tid * 4;
    int4 lab = *(const int4*)(tgtb + base);
    float s0 = 0.f, s1 = 0.f, s2 = 0.f, s3 = 0.f;
#pragma unroll
    for (int f = 0; f < NF; ++f) {
        float4 p = *(const float4*)(predb + f * NPIX + base);
        float d0 = s_means[f * C + lab.x] - p.x;
        float d1 = s_means[f * C + lab.y] - p.y;
        float d2 = s_means[f * C + lab.z] - p.z;
        float d3 = s_means[f * C + lab.w] - p.w;
        s0 += d0 * d0; s1 += d1 * d1; s2 += d2 * d2; s3 += d3 * d3;
    }
    float t0 = fminf(fmaxf(sqrtf(s0) - 0.5f, 0.0f), 100000.0f);
    float t1 = fminf(fmaxf(sqrtf(s1) - 0.5f, 0.0f), 100000.0f);
    float t2 = fminf(fmaxf(sqrtf(s2) - 0.5f, 0.0f), 100000.0f);
    float t3 = fminf(fmaxf(sqrtf(s3) - 0.5f, 0.0f), 100000.0f);
    float acc = t0 * t0 + t1 * t1 + t2 * t2 + t3 * t3;

#pragma unroll
    for (int off = 32; off > 0; off >>= 1) acc += __shfl_down(acc, off);
    const int lane = tid & 63, wave = tid >> 6;
    if (lane == 0) s_red[wave] = acc;
    __syncthreads();
    if (tid == 0) {
        float tot = s_red[0] + s_red[1] + s_red[2] + s_red[3];
        pout[b * DG + blockIdx.x] = tot * s_invs * 0.125f;
    }
}

// One block, 512 threads: sum the 1024 dist partials, plain store to out.
__global__ void final_kernel(const float* __restrict__ pout, float* __restrict__ out) {
    __shared__ float sr[8];
    const int t = threadIdx.x;
    float v = pout[t] + pout[t + 512];
#pragma unroll
    for (int off = 32; off > 0; off >>= 1) v += __shfl_xor(v, off);
    if ((t & 63) == 0) sr[t >> 6] = v;
    __syncthreads();
    if (t == 0) {
        float s = 0.0f;
#pragma unroll
        for (int i = 0; i < 8; ++i) s += sr[i];
        out[0] = s;
    }
}

extern "C" void kernel_launch(void* const* d_in, const int* in_sizes, int n_in,
                              void* d_out, int out_size, void* d_ws, size_t ws_size,
                              hipStream_t stream) {
    const float* pred = (const float*)d_in[0];
    const int*   tgt  = (const int*)d_in[1];
    float* out = (float*)d_out;
    float* ws  = (float*)d_ws;

    sums_kernel<<<dim3(CH, NF, NB), dim3(256), 0, stream>>>(pred, tgt, ws);
    dist_kernel<<<dim3(DG, NB), dim3(256), 0, stream>>>(pred, tgt, ws, ws + WS_POUT);
    final_kernel<<<dim3(1), dim3(512), 0, stream>>>(ws + WS_POUT, out);
}